// Round 1
// baseline (522.409 us; speedup 1.0000x reference)
//
#include <hip/hip_runtime.h>
#include <math.h>

#define B_   32
#define C_   64
#define F_   128
#define TP_  32
#define G_   (B_*TP_)      // 1024 graphs
#define N1_  (G_*C_)       // 65536 nodes layer 1
#define NHID 256
#define NOUT 128
#define E_   512
#define K1_  52            // ceil(0.8*64)
#define K2_  42            // ceil(0.8*52)
#define N2_  (G_*K1_)      // 53248 nodes layer 2

// ---------------- transpose h (B,C,F,TP) -> x0 (G*C, F), g = b*TP+tp ----------------
__global__ __launch_bounds__(256) void transpose_h(const float* __restrict__ h,
                                                   float* __restrict__ x0) {
  int bc = blockIdx.x;            // b*C_ + c
  int f0 = blockIdx.y * 32;
  __shared__ float t[32][33];
  int tp = threadIdx.x;
  for (int fi = threadIdx.y; fi < 32; fi += 8)
    t[fi][tp] = h[((size_t)bc * F_ + f0 + fi) * TP_ + tp];
  __syncthreads();
  int b = bc / C_, c = bc % C_;
  int f = threadIdx.x;
  for (int tpi = threadIdx.y; tpi < 32; tpi += 8) {
    int g = b * TP_ + tpi;
    x0[((size_t)g * C_ + c) * F_ + f0 + f] = t[f][tpi];
  }
}

// ---------------- build shared 64x64 A1 (edge weights) and As1 (binary) --------------
__global__ __launch_bounds__(64) void build_A1(const int* __restrict__ ei,
                                               const float* __restrict__ ew,
                                               float* __restrict__ A1,
                                               float* __restrict__ As1) {
  __shared__ float dis[C_], diss[C_], ews[E_];
  __shared__ int rs[E_], cs[E_];
  __shared__ float A1s[C_*C_], As1s[C_*C_];
  int t = threadIdx.x;  // 64 threads
  for (int e = t; e < E_; e += 64) { rs[e] = ei[e]; cs[e] = ei[E_ + e]; ews[e] = ew[e]; }
  for (int i = t; i < C_*C_; i += 64) { A1s[i] = 0.f; As1s[i] = 0.f; }
  __syncthreads();
  {
    float dg = 1.f, dgs = 1.f;  // self-loop weight 1
    for (int e = 0; e < E_; ++e)
      if (cs[e] == t) { dg += ews[e]; dgs += 1.f; }
    dis[t] = rsqrtf(dg); diss[t] = rsqrtf(dgs);
  }
  __syncthreads();
  // thread t owns target row t (deterministic, race-free)
  for (int e = 0; e < E_; ++e) {
    if (cs[e] == t) {
      int r = rs[e];
      A1s[t*C_ + r]  += dis[r] * ews[e] * dis[t];
      As1s[t*C_ + r] += diss[r] * diss[t];
    }
  }
  A1s[t*C_ + t]  += dis[t] * dis[t];
  As1s[t*C_ + t] += diss[t] * diss[t];
  __syncthreads();
  for (int i = t; i < C_*C_; i += 64) { A1[i] = A1s[i]; As1[i] = As1s[i]; }
}

// ---------------- generic f32 GEMM: C[MxN] = A[MxK] @ B[KxN]; M%64==0, N%64==0, K%16==0
__global__ __launch_bounds__(256) void gemm_f32(const float* __restrict__ A,
                                                const float* __restrict__ Bm,
                                                float* __restrict__ Cm,
                                                int M, int N, int K) {
  __shared__ __align__(16) float As[16][68];  // [k][m]
  __shared__ __align__(16) float Bs[16][68];  // [k][n]
  int t = threadIdx.x;
  int row0 = blockIdx.x * 64, col0 = blockIdx.y * 64;
  int tm = t >> 2, tq = t & 3;   // A loads
  int lk = t >> 4, ln = t & 15;  // B loads
  int ty = t >> 4, tx = t & 15;  // 4x4 microtile
  float acc[4][4] = {};
  for (int k0 = 0; k0 < K; k0 += 16) {
    float4 av = *(const float4*)(A + (size_t)(row0 + tm) * K + k0 + 4*tq);
    As[4*tq+0][tm] = av.x; As[4*tq+1][tm] = av.y;
    As[4*tq+2][tm] = av.z; As[4*tq+3][tm] = av.w;
    float4 bv = *(const float4*)(Bm + (size_t)(k0 + lk) * N + col0 + 4*ln);
    *(float4*)&Bs[lk][4*ln] = bv;
    __syncthreads();
#pragma unroll
    for (int kk = 0; kk < 16; ++kk) {
      float4 a = *(const float4*)&As[kk][4*ty];
      float4 b = *(const float4*)&Bs[kk][4*tx];
      acc[0][0]=fmaf(a.x,b.x,acc[0][0]); acc[0][1]=fmaf(a.x,b.y,acc[0][1]);
      acc[0][2]=fmaf(a.x,b.z,acc[0][2]); acc[0][3]=fmaf(a.x,b.w,acc[0][3]);
      acc[1][0]=fmaf(a.y,b.x,acc[1][0]); acc[1][1]=fmaf(a.y,b.y,acc[1][1]);
      acc[1][2]=fmaf(a.y,b.z,acc[1][2]); acc[1][3]=fmaf(a.y,b.w,acc[1][3]);
      acc[2][0]=fmaf(a.z,b.x,acc[2][0]); acc[2][1]=fmaf(a.z,b.y,acc[2][1]);
      acc[2][2]=fmaf(a.z,b.z,acc[2][2]); acc[2][3]=fmaf(a.z,b.w,acc[2][3]);
      acc[3][0]=fmaf(a.w,b.x,acc[3][0]); acc[3][1]=fmaf(a.w,b.y,acc[3][1]);
      acc[3][2]=fmaf(a.w,b.z,acc[3][2]); acc[3][3]=fmaf(a.w,b.w,acc[3][3]);
    }
    __syncthreads();
  }
  for (int i = 0; i < 4; ++i) {
    float4 v = make_float4(acc[i][0], acc[i][1], acc[i][2], acc[i][3]);
    *(float4*)(Cm + (size_t)(row0 + 4*ty + i) * N + col0 + 4*tx) = v;
  }
}

// ---------------- layer1: y1 = prelu(bn(A1 @ xw1 + b1)) per graph ----------------
__global__ __launch_bounds__(256) void agg1_k(const float* __restrict__ xw,
                                              const float* __restrict__ A,
                                              const float* __restrict__ bias,
                                              const float* __restrict__ gamma,
                                              const float* __restrict__ beta,
                                              const float* __restrict__ mean,
                                              const float* __restrict__ var,
                                              const float* __restrict__ pa,
                                              float* __restrict__ y) {
  int g = blockIdx.x, t = threadIdx.x;
  __shared__ __align__(16) float xs[64*128];
  __shared__ float Ash[64*64];
  __shared__ __align__(16) float sc[NHID], sh[NHID];
  {
    float s = gamma[t] * rsqrtf(var[t] + 1e-5f);
    sc[t] = s;
    sh[t] = (bias[t] - mean[t]) * s + beta[t];
  }
  for (int i = t; i < 64*64; i += 256) Ash[i] = A[i];
  const float a = pa[0];
  for (int half = 0; half < 2; ++half) {
    if (half) __syncthreads();
    for (int i = t; i < 64*32; i += 256) {
      int c = i >> 5, q = i & 31;
      ((float4*)xs)[c*32 + q] =
          *(const float4*)(xw + ((size_t)g*64 + c)*NHID + half*128 + q*4);
    }
    __syncthreads();
    for (int i = t; i < 64*32; i += 256) {
      int c = i >> 5, fq = i & 31;
      float4 acc = make_float4(0.f, 0.f, 0.f, 0.f);
      for (int j = 0; j < 64; ++j) {
        float aj = Ash[c*64 + j];
        float4 xv = ((const float4*)xs)[j*32 + fq];
        acc.x = fmaf(aj, xv.x, acc.x); acc.y = fmaf(aj, xv.y, acc.y);
        acc.z = fmaf(aj, xv.z, acc.z); acc.w = fmaf(aj, xv.w, acc.w);
      }
      int fo4 = half*32 + fq;
      float4 s4 = ((const float4*)sc)[fo4];
      float4 h4 = ((const float4*)sh)[fo4];
      float4 o;
      o.x = acc.x*s4.x + h4.x; o.y = acc.y*s4.y + h4.y;
      o.z = acc.z*s4.z + h4.z; o.w = acc.w*s4.w + h4.w;
      o.x = o.x >= 0.f ? o.x : a*o.x; o.y = o.y >= 0.f ? o.y : a*o.y;
      o.z = o.z >= 0.f ? o.z : a*o.z; o.w = o.w >= 0.f ? o.w : a*o.w;
      *(float4*)(y + ((size_t)g*64 + c)*NHID + half*128 + fq*4) = o;
    }
  }
}

// ---------------- score1: s = As1 @ (y1 . pool1_w) + b ----------------
__global__ __launch_bounds__(256) void score1_k(const float* __restrict__ y1,
                                                const float* __restrict__ As1,
                                                const float* __restrict__ pw,
                                                const float* __restrict__ pb,
                                                float* __restrict__ score) {
  int g = blockIdx.x, t = threadIdx.x;
  __shared__ float sp[64];
  int c = t >> 2, q = t & 3;
  const float* row = y1 + ((size_t)g*64 + c) * NHID;
  float acc = 0.f;
  for (int f = q*64; f < q*64 + 64; f += 4) {
    float4 v = *(const float4*)(row + f);
    float4 wv = *(const float4*)(pw + f);
    acc += v.x*wv.x + v.y*wv.y + v.z*wv.z + v.w*wv.w;
  }
  acc += __shfl_xor(acc, 1);
  acc += __shfl_xor(acc, 2);
  if (q == 0) sp[c] = acc;
  __syncthreads();
  if (t < 64) {
    float s = 0.f;
    for (int j = 0; j < 64; ++j) s = fmaf(As1[t*64 + j], sp[j], s);
    score[g*64 + t] = s + pb[0];
  }
}

// ---------------- topk1: stable top-52, gate by tanh(score), write xk1, newidx -------
__global__ __launch_bounds__(256) void topk1_gate(const float* __restrict__ score,
                                                  const float* __restrict__ y1,
                                                  float* __restrict__ xk1,
                                                  int* __restrict__ nidx) {
  int g = blockIdx.x, t = threadIdx.x;
  __shared__ float s[64];
  __shared__ int perm[K1_];
  __shared__ float gate[K1_];
  if (t < 64) s[t] = score[g*64 + t];
  __syncthreads();
  if (t < 64) {
    float si = s[t];
    int rank = 0;
    for (int j = 0; j < 64; ++j) {
      float sj = s[j];
      rank += (sj > si) || (sj == si && j < t);
    }
    nidx[g*64 + t] = (rank < K1_) ? rank : -1;
    if (rank < K1_) { perm[rank] = t; gate[rank] = tanhf(si); }
  }
  __syncthreads();
  for (int i = t; i < K1_*(NHID/4); i += 256) {
    int r = i / (NHID/4), q = i % (NHID/4);
    int old = perm[r];
    float4 v = ((const float4*)(y1 + ((size_t)g*64 + old)*NHID))[q];
    float gt = gate[r];
    v.x *= gt; v.y *= gt; v.z *= gt; v.w *= gt;
    ((float4*)(xk1 + ((size_t)g*K1_ + r)*NHID))[q] = v;
  }
}

// ---------------- build per-graph 52x52 A2 (edge weights) and As2 (binary) -----------
__global__ __launch_bounds__(256) void build_A2(const int* __restrict__ ei,
                                                const float* __restrict__ ew,
                                                const int* __restrict__ nidx,
                                                float* __restrict__ A2,
                                                float* __restrict__ As2) {
  int g = blockIdx.x, t = threadIdx.x;
  __shared__ float A2s[K1_*K1_], As2s[K1_*K1_];
  __shared__ float dis[K1_], diss[K1_], ews[E_];
  __shared__ int nrs[E_], ncs[E_];
  for (int i = t; i < K1_*K1_; i += 256) { A2s[i] = 0.f; As2s[i] = 0.f; }
  for (int e = t; e < E_; e += 256) {
    int nr = nidx[g*64 + ei[e]];
    int nc = nidx[g*64 + ei[E_ + e]];
    bool v = (nr >= 0) && (nc >= 0);
    nrs[e] = v ? nr : -1;
    ncs[e] = nc;
    ews[e] = ew[e];
  }
  __syncthreads();
  if (t < K1_) {
    float dg = 1.f, dgs = 1.f;
    for (int e = 0; e < E_; ++e)
      if (ncs[e] == t && nrs[e] >= 0) { dg += ews[e]; dgs += 1.f; }
    dis[t] = rsqrtf(dg); diss[t] = rsqrtf(dgs);
  }
  __syncthreads();
  if (t < K1_) {
    for (int e = 0; e < E_; ++e) {
      if (ncs[e] == t && nrs[e] >= 0) {
        int r = nrs[e];
        A2s[t*K1_ + r]  += dis[r] * ews[e] * dis[t];
        As2s[t*K1_ + r] += diss[r] * diss[t];
      }
    }
    A2s[t*K1_ + t]  += dis[t] * dis[t];
    As2s[t*K1_ + t] += diss[t] * diss[t];
  }
  __syncthreads();
  float* A2g  = A2 + (size_t)g * (K1_*K1_);
  float* As2g = As2 + (size_t)g * (K1_*K1_);
  for (int i = t; i < K1_*K1_; i += 256) { A2g[i] = A2s[i]; As2g[i] = As2s[i]; }
}

// ---------------- layer2: y2 = prelu(bn(A2_g @ xw2_g + b2)) per graph ----------------
__global__ __launch_bounds__(256) void agg2_k(const float* __restrict__ xw,
                                              const float* __restrict__ A2,
                                              const float* __restrict__ bias,
                                              const float* __restrict__ gamma,
                                              const float* __restrict__ beta,
                                              const float* __restrict__ mean,
                                              const float* __restrict__ var,
                                              const float* __restrict__ pa,
                                              float* __restrict__ y) {
  int g = blockIdx.x, t = threadIdx.x;
  __shared__ __align__(16) float xs[K1_*NOUT];
  __shared__ float Ash[K1_*K1_];
  __shared__ __align__(16) float sc[NOUT], sh[NOUT];
  if (t < NOUT) {
    float s = gamma[t] * rsqrtf(var[t] + 1e-5f);
    sc[t] = s;
    sh[t] = (bias[t] - mean[t]) * s + beta[t];
  }
  const float* Ag = A2 + (size_t)g * (K1_*K1_);
  for (int i = t; i < K1_*K1_; i += 256) Ash[i] = Ag[i];
  for (int i = t; i < K1_*(NOUT/4); i += 256)
    ((float4*)xs)[i] = ((const float4*)(xw + (size_t)g*K1_*NOUT))[i];
  const float a = pa[0];
  __syncthreads();
  for (int i = t; i < K1_*(NOUT/4); i += 256) {
    int c = i >> 5, fq = i & 31;
    float4 acc = make_float4(0.f, 0.f, 0.f, 0.f);
    for (int j = 0; j < K1_; ++j) {
      float aj = Ash[c*K1_ + j];
      float4 xv = ((const float4*)xs)[j*32 + fq];
      acc.x = fmaf(aj, xv.x, acc.x); acc.y = fmaf(aj, xv.y, acc.y);
      acc.z = fmaf(aj, xv.z, acc.z); acc.w = fmaf(aj, xv.w, acc.w);
    }
    float4 s4 = ((const float4*)sc)[fq];
    float4 h4 = ((const float4*)sh)[fq];
    float4 o;
    o.x = acc.x*s4.x + h4.x; o.y = acc.y*s4.y + h4.y;
    o.z = acc.z*s4.z + h4.z; o.w = acc.w*s4.w + h4.w;
    o.x = o.x >= 0.f ? o.x : a*o.x; o.y = o.y >= 0.f ? o.y : a*o.y;
    o.z = o.z >= 0.f ? o.z : a*o.z; o.w = o.w >= 0.f ? o.w : a*o.w;
    *(float4*)(y + ((size_t)g*K1_ + c)*NOUT + fq*4) = o;
  }
}

// ---------------- score2 ----------------
__global__ __launch_bounds__(256) void score2_k(const float* __restrict__ y2,
                                                const float* __restrict__ As2,
                                                const float* __restrict__ pw,
                                                const float* __restrict__ pb,
                                                float* __restrict__ score) {
  int g = blockIdx.x, t = threadIdx.x;
  __shared__ float sp[K1_];
  int c = t >> 2, q = t & 3;
  float acc = 0.f;
  if (c < K1_) {
    const float* row = y2 + ((size_t)g*K1_ + c) * NOUT;
    for (int f = q*32; f < q*32 + 32; f += 4) {
      float4 v = *(const float4*)(row + f);
      float4 wv = *(const float4*)(pw + f);
      acc += v.x*wv.x + v.y*wv.y + v.z*wv.z + v.w*wv.w;
    }
  }
  acc += __shfl_xor(acc, 1);
  acc += __shfl_xor(acc, 2);
  if (q == 0 && c < K1_) sp[c] = acc;
  __syncthreads();
  if (t < K1_) {
    const float* Ar = As2 + ((size_t)g*K1_ + t) * K1_;
    float s = 0.f;
    for (int j = 0; j < K1_; ++j) s = fmaf(Ar[j], sp[j], s);
    score[g*K1_ + t] = s + pb[0];
  }
}

// ---------------- topk2 + gate + write x and z directly to d_out ----------------
__global__ __launch_bounds__(128) void topk2_out(const float* __restrict__ score,
                                                 const float* __restrict__ y2,
                                                 float* __restrict__ out) {
  int g = blockIdx.x, t = threadIdx.x;  // 128 threads, t == feature index
  __shared__ float s[K1_];
  __shared__ int perm[K2_];
  __shared__ float gate[K2_];
  if (t < K1_) s[t] = score[g*K1_ + t];
  __syncthreads();
  if (t < K1_) {
    float si = s[t];
    int rank = 0;
    for (int j = 0; j < K1_; ++j) {
      float sj = s[j];
      rank += (sj > si) || (sj == si && j < t);
    }
    if (rank < K2_) { perm[rank] = t; gate[rank] = tanhf(si); }
  }
  __syncthreads();
  float zacc = 0.f;
  float* xout = out + (size_t)g * K2_ * NOUT;
  for (int r = 0; r < K2_; ++r) {
    float v = y2[((size_t)g*K1_ + perm[r]) * NOUT + t] * gate[r];
    xout[(size_t)r * NOUT + t] = v;
    zacc += v;
  }
  out[(size_t)G_*K2_*NOUT + (size_t)g*NOUT + t] = zacc * (1.0f / (float)K2_);
}

extern "C" void kernel_launch(void* const* d_in, const int* in_sizes, int n_in,
                              void* d_out, int out_size, void* d_ws, size_t ws_size,
                              hipStream_t stream) {
  const float* h    = (const float*)d_in[0];
  const int*   ei   = (const int*)  d_in[1];
  const float* ew   = (const float*)d_in[2];
  const float* gc1w = (const float*)d_in[3];
  const float* gc1b = (const float*)d_in[4];
  const float* bn1g = (const float*)d_in[5];
  const float* bn1b = (const float*)d_in[6];
  const float* bn1m = (const float*)d_in[7];
  const float* bn1v = (const float*)d_in[8];
  const float* pr1a = (const float*)d_in[9];
  const float* p1w  = (const float*)d_in[10];
  const float* p1b  = (const float*)d_in[11];
  const float* gc2w = (const float*)d_in[12];
  const float* gc2b = (const float*)d_in[13];
  const float* bn2g = (const float*)d_in[14];
  const float* bn2b = (const float*)d_in[15];
  const float* bn2m = (const float*)d_in[16];
  const float* bn2v = (const float*)d_in[17];
  const float* pr2a = (const float*)d_in[18];
  const float* p2w  = (const float*)d_in[19];
  const float* p2b  = (const float*)d_in[20];

  float* w = (float*)d_ws;
  // layout (floats); reuse: xk1 over xw1, xw2 over x0, y2 over y1
  float* A1   = w;                      // 4096
  float* As1  = w + 4096;               // 4096
  float* sc1  = w + 8192;               // 65536
  int*   nidx = (int*)(w + 73728);      // 65536
  float* sc2  = w + 139264;             // 53248
  float* x0   = w + 196608;             // 8388608
  float* xw1  = w + 8585216;            // 16777216
  float* y1   = w + 25362432;           // 16777216
  float* A2   = w + 42139648;           // 2768896
  float* As2  = w + 44908544;           // 2768896  -> end 47677440 floats (~182 MiB)
  float* xk1  = xw1;
  float* xw2  = x0;
  float* y2   = y1;

  transpose_h<<<dim3(B_*C_, F_/32), dim3(32, 8), 0, stream>>>(h, x0);
  build_A1<<<1, 64, 0, stream>>>(ei, ew, A1, As1);
  gemm_f32<<<dim3(N1_/64, NHID/64), 256, 0, stream>>>(x0, gc1w, xw1, N1_, NHID, F_);
  agg1_k<<<G_, 256, 0, stream>>>(xw1, A1, gc1b, bn1g, bn1b, bn1m, bn1v, pr1a, y1);
  score1_k<<<G_, 256, 0, stream>>>(y1, As1, p1w, p1b, sc1);
  topk1_gate<<<G_, 256, 0, stream>>>(sc1, y1, xk1, nidx);
  build_A2<<<G_, 256, 0, stream>>>(ei, ew, nidx, A2, As2);
  gemm_f32<<<dim3(N2_/64, NOUT/64), 256, 0, stream>>>(xk1, gc2w, xw2, N2_, NOUT, NHID);
  agg2_k<<<G_, 256, 0, stream>>>(xw2, A2, gc2b, bn2g, bn2b, bn2m, bn2v, pr2a, y2);
  score2_k<<<G_, 256, 0, stream>>>(y2, As2, p2w, p2b, sc2);
  topk2_out<<<G_, 128, 0, stream>>>(sc2, y2, (float*)d_out);
}

// Round 2
// 308.273 us; speedup vs baseline: 1.6946x; 1.6946x over previous
//
#include <hip/hip_runtime.h>
#include <math.h>

#define B_   32
#define C_   64
#define F_   128
#define TP_  32
#define G_   (B_*TP_)      // 1024 graphs
#define N1_  (G_*C_)       // 65536 nodes layer 1
#define NHID 256
#define NOUT 128
#define E_   512
#define K1_  52            // ceil(0.8*64)
#define K2_  42            // ceil(0.8*52)
#define N2_  (G_*K1_)      // 53248 nodes layer 2

// ---------------- transpose h (B,C,F,TP) -> x0 (G*C, F), g = b*TP+tp ----------------
__global__ __launch_bounds__(256) void transpose_h(const float* __restrict__ h,
                                                   float* __restrict__ x0) {
  int bc = blockIdx.x;            // b*C_ + c
  int f0 = blockIdx.y * 32;
  __shared__ float t[32][33];
  int tp = threadIdx.x;
  for (int fi = threadIdx.y; fi < 32; fi += 8)
    t[fi][tp] = h[((size_t)bc * F_ + f0 + fi) * TP_ + tp];
  __syncthreads();
  int b = bc / C_, c = bc % C_;
  int f = threadIdx.x;
  for (int tpi = threadIdx.y; tpi < 32; tpi += 8) {
    int g = b * TP_ + tpi;
    x0[((size_t)g * C_ + c) * F_ + f0 + f] = t[f][tpi];
  }
}

// -------- build shared 64x64 A1 (edge weights) and As1 (binary), edge-parallel -------
__global__ __launch_bounds__(256) void build_A1(const int* __restrict__ ei,
                                                const float* __restrict__ ew,
                                                float* __restrict__ A1,
                                                float* __restrict__ As1) {
  __shared__ float A1s[C_*C_], As1s[C_*C_];
  __shared__ float dg[C_], dgs[C_], dis[C_], diss[C_];
  int t = threadIdx.x;
  for (int i = t; i < C_*C_; i += 256) { A1s[i] = 0.f; As1s[i] = 0.f; }
  if (t < C_) { dg[t] = 1.f; dgs[t] = 1.f; }   // self-loop weight 1
  int r0[2], c0[2]; float w0[2];
#pragma unroll
  for (int p = 0; p < 2; ++p) {
    int e = t + p*256;
    r0[p] = ei[e]; c0[p] = ei[E_ + e]; w0[p] = ew[e];
  }
  __syncthreads();
#pragma unroll
  for (int p = 0; p < 2; ++p) {
    atomicAdd(&dg[c0[p]], w0[p]);
    atomicAdd(&dgs[c0[p]], 1.f);
  }
  __syncthreads();
  if (t < C_) { dis[t] = rsqrtf(dg[t]); diss[t] = rsqrtf(dgs[t]); }
  __syncthreads();
#pragma unroll
  for (int p = 0; p < 2; ++p) {
    int r = r0[p], c = c0[p];
    atomicAdd(&A1s[c*C_ + r],  dis[r] * w0[p] * dis[c]);
    atomicAdd(&As1s[c*C_ + r], diss[r] * diss[c]);
  }
  if (t < C_) {
    atomicAdd(&A1s[t*C_ + t],  dis[t] * dis[t]);
    atomicAdd(&As1s[t*C_ + t], diss[t] * diss[t]);
  }
  __syncthreads();
  for (int i = t; i < C_*C_; i += 256) { A1[i] = A1s[i]; As1[i] = As1s[i]; }
}

// ---------------- generic f32 GEMM: C = A[MxK] @ B[KxN], BK=16, 256 threads ----------
// microtile TM x TN split as 2x2 (or 2x1) blocks of 4x4 at offsets {0, BM/2}/{0, BN/2}
template<int BM, int BN, int TM, int TN>
__global__ __launch_bounds__(256) void gemm_t(const float* __restrict__ A,
                                              const float* __restrict__ Bm,
                                              float* __restrict__ Cm,
                                              int M, int N, int K) {
  constexpr int BK = 16;
  __shared__ __align__(16) float As[BK][BM + 4];
  __shared__ __align__(16) float Bs[BK][BN + 4];
  int t = threadIdx.x;
  int row0 = blockIdx.x * BM, col0 = blockIdx.y * BN;
  constexpr int TX = BN / TN;      // 16
  int tx = t % TX, ty = t / TX;    // ty in [0, BM/TM)
  float acc[TM][TN] = {};
  for (int k0 = 0; k0 < K; k0 += BK) {
    // A tile: BM x BK
#pragma unroll
    for (int p = 0; p < BM/64; ++p) {
      int rm = (t >> 2) + p*64, tq = t & 3;
      float4 av = *(const float4*)(A + (size_t)(row0 + rm) * K + k0 + 4*tq);
      As[4*tq+0][rm] = av.x; As[4*tq+1][rm] = av.y;
      As[4*tq+2][rm] = av.z; As[4*tq+3][rm] = av.w;
    }
    // B tile: BK x BN
#pragma unroll
    for (int p = 0; p < BK*BN/1024; ++p) {
      int rk = t / (BN/4) + p * (1024/BN);
      int cn = (t % (BN/4)) * 4;
      *(float4*)&Bs[rk][cn] = *(const float4*)(Bm + (size_t)(k0 + rk) * N + col0 + cn);
    }
    __syncthreads();
#pragma unroll
    for (int kk = 0; kk < BK; ++kk) {
      float a[TM], b[TN];
      *(float4*)&a[0] = *(const float4*)&As[kk][4*ty];
      if (TM == 8) *(float4*)&a[4] = *(const float4*)&As[kk][BM/2 + 4*ty];
      *(float4*)&b[0] = *(const float4*)&Bs[kk][4*tx];
      if (TN == 8) *(float4*)&b[4] = *(const float4*)&Bs[kk][BN/2 + 4*tx];
#pragma unroll
      for (int i = 0; i < TM; ++i)
#pragma unroll
        for (int j = 0; j < TN; ++j)
          acc[i][j] = fmaf(a[i], b[j], acc[i][j]);
    }
    __syncthreads();
  }
#pragma unroll
  for (int ih = 0; ih < TM/4; ++ih)
#pragma unroll
    for (int i = 0; i < 4; ++i) {
      int r = row0 + ih*(BM/2) + 4*ty + i;
#pragma unroll
      for (int jh = 0; jh < TN/4; ++jh) {
        float4 v = make_float4(acc[ih*4+i][jh*4+0], acc[ih*4+i][jh*4+1],
                               acc[ih*4+i][jh*4+2], acc[ih*4+i][jh*4+3]);
        *(float4*)(Cm + (size_t)r * N + col0 + jh*(BN/2) + 4*tx) = v;
      }
    }
}

// ---------------- layer1: y1 = prelu(bn(A1 @ xw1 + b1)) per graph ----------------
__global__ __launch_bounds__(256) void agg1_k(const float* __restrict__ xw,
                                              const float* __restrict__ A,
                                              const float* __restrict__ bias,
                                              const float* __restrict__ gamma,
                                              const float* __restrict__ beta,
                                              const float* __restrict__ mean,
                                              const float* __restrict__ var,
                                              const float* __restrict__ pa,
                                              float* __restrict__ y) {
  int g = blockIdx.x, t = threadIdx.x;
  __shared__ __align__(16) float xs[64*128];
  __shared__ float Ash[64*64];
  __shared__ __align__(16) float sc[NHID], sh[NHID];
  {
    float s = gamma[t] * rsqrtf(var[t] + 1e-5f);
    sc[t] = s;
    sh[t] = (bias[t] - mean[t]) * s + beta[t];
  }
  for (int i = t; i < 64*64; i += 256) Ash[i] = A[i];
  const float a = pa[0];
  for (int half = 0; half < 2; ++half) {
    if (half) __syncthreads();
    for (int i = t; i < 64*32; i += 256) {
      int c = i >> 5, q = i & 31;
      ((float4*)xs)[c*32 + q] =
          *(const float4*)(xw + ((size_t)g*64 + c)*NHID + half*128 + q*4);
    }
    __syncthreads();
    for (int i = t; i < 64*32; i += 256) {
      int c = i >> 5, fq = i & 31;
      float4 acc = make_float4(0.f, 0.f, 0.f, 0.f);
      for (int j = 0; j < 64; ++j) {
        float aj = Ash[c*64 + j];
        float4 xv = ((const float4*)xs)[j*32 + fq];
        acc.x = fmaf(aj, xv.x, acc.x); acc.y = fmaf(aj, xv.y, acc.y);
        acc.z = fmaf(aj, xv.z, acc.z); acc.w = fmaf(aj, xv.w, acc.w);
      }
      int fo4 = half*32 + fq;
      float4 s4 = ((const float4*)sc)[fo4];
      float4 h4 = ((const float4*)sh)[fo4];
      float4 o;
      o.x = acc.x*s4.x + h4.x; o.y = acc.y*s4.y + h4.y;
      o.z = acc.z*s4.z + h4.z; o.w = acc.w*s4.w + h4.w;
      o.x = o.x >= 0.f ? o.x : a*o.x; o.y = o.y >= 0.f ? o.y : a*o.y;
      o.z = o.z >= 0.f ? o.z : a*o.z; o.w = o.w >= 0.f ? o.w : a*o.w;
      *(float4*)(y + ((size_t)g*64 + c)*NHID + half*128 + fq*4) = o;
    }
  }
}

// ---------------- score1: s = As1 @ (y1 . pool1_w) + b ----------------
__global__ __launch_bounds__(256) void score1_k(const float* __restrict__ y1,
                                                const float* __restrict__ As1,
                                                const float* __restrict__ pw,
                                                const float* __restrict__ pb,
                                                float* __restrict__ score) {
  int g = blockIdx.x, t = threadIdx.x;
  __shared__ float sp[64];
  int c = t >> 2, q = t & 3;
  const float* row = y1 + ((size_t)g*64 + c) * NHID;
  float acc = 0.f;
  for (int f = q*64; f < q*64 + 64; f += 4) {
    float4 v = *(const float4*)(row + f);
    float4 wv = *(const float4*)(pw + f);
    acc += v.x*wv.x + v.y*wv.y + v.z*wv.z + v.w*wv.w;
  }
  acc += __shfl_xor(acc, 1);
  acc += __shfl_xor(acc, 2);
  if (q == 0) sp[c] = acc;
  __syncthreads();
  if (t < 64) {
    float s = 0.f;
    for (int j = 0; j < 64; ++j) s = fmaf(As1[t*64 + j], sp[j], s);
    score[g*64 + t] = s + pb[0];
  }
}

// ---------------- topk1: stable top-52, gate by tanh(score), write xk1, newidx -------
__global__ __launch_bounds__(256) void topk1_gate(const float* __restrict__ score,
                                                  const float* __restrict__ y1,
                                                  float* __restrict__ xk1,
                                                  int* __restrict__ nidx) {
  int g = blockIdx.x, t = threadIdx.x;
  __shared__ float s[64];
  __shared__ int perm[K1_];
  __shared__ float gate[K1_];
  if (t < 64) s[t] = score[g*64 + t];
  __syncthreads();
  if (t < 64) {
    float si = s[t];
    int rank = 0;
    for (int j = 0; j < 64; ++j) {
      float sj = s[j];
      rank += (sj > si) || (sj == si && j < t);
    }
    nidx[g*64 + t] = (rank < K1_) ? rank : -1;
    if (rank < K1_) { perm[rank] = t; gate[rank] = tanhf(si); }
  }
  __syncthreads();
  for (int i = t; i < K1_*(NHID/4); i += 256) {
    int r = i / (NHID/4), q = i % (NHID/4);
    int old = perm[r];
    float4 v = ((const float4*)(y1 + ((size_t)g*64 + old)*NHID))[q];
    float gt = gate[r];
    v.x *= gt; v.y *= gt; v.z *= gt; v.w *= gt;
    ((float4*)(xk1 + ((size_t)g*K1_ + r)*NHID))[q] = v;
  }
}

// -------- build per-graph 52x52 A2 (edge weights) and As2 (binary), edge-parallel ----
__global__ __launch_bounds__(256) void build_A2(const int* __restrict__ ei,
                                                const float* __restrict__ ew,
                                                const int* __restrict__ nidx,
                                                float* __restrict__ A2,
                                                float* __restrict__ As2) {
  int g = blockIdx.x, t = threadIdx.x;
  __shared__ float A2s[K1_*K1_], As2s[K1_*K1_];
  __shared__ float dg[K1_], dgs[K1_], dis[K1_], diss[K1_];
  __shared__ int nm[C_];
  for (int i = t; i < K1_*K1_; i += 256) { A2s[i] = 0.f; As2s[i] = 0.f; }
  if (t < C_) nm[t] = nidx[g*C_ + t];
  if (t < K1_) { dg[t] = 1.f; dgs[t] = 1.f; }
  int eR[2], eC[2]; float eW[2];
#pragma unroll
  for (int p = 0; p < 2; ++p) {
    int e = t + p*256;
    eR[p] = ei[e]; eC[p] = ei[E_ + e]; eW[p] = ew[e];
  }
  __syncthreads();
  int nr[2], nc[2]; bool v[2];
#pragma unroll
  for (int p = 0; p < 2; ++p) {
    nr[p] = nm[eR[p]]; nc[p] = nm[eC[p]];
    v[p] = (nr[p] >= 0) && (nc[p] >= 0);
    if (v[p]) { atomicAdd(&dg[nc[p]], eW[p]); atomicAdd(&dgs[nc[p]], 1.f); }
  }
  __syncthreads();
  if (t < K1_) { dis[t] = rsqrtf(dg[t]); diss[t] = rsqrtf(dgs[t]); }
  __syncthreads();
#pragma unroll
  for (int p = 0; p < 2; ++p) {
    if (v[p]) {
      atomicAdd(&A2s[nc[p]*K1_ + nr[p]],  dis[nr[p]] * eW[p] * dis[nc[p]]);
      atomicAdd(&As2s[nc[p]*K1_ + nr[p]], diss[nr[p]] * diss[nc[p]]);
    }
  }
  if (t < K1_) {
    atomicAdd(&A2s[t*K1_ + t],  dis[t] * dis[t]);
    atomicAdd(&As2s[t*K1_ + t], diss[t] * diss[t]);
  }
  __syncthreads();
  float* A2g  = A2 + (size_t)g * (K1_*K1_);
  float* As2g = As2 + (size_t)g * (K1_*K1_);
  for (int i = t; i < K1_*K1_; i += 256) { A2g[i] = A2s[i]; As2g[i] = As2s[i]; }
}

// ---------------- layer2: y2 = prelu(bn(A2_g @ xw2_g + b2)) per graph ----------------
__global__ __launch_bounds__(256) void agg2_k(const float* __restrict__ xw,
                                              const float* __restrict__ A2,
                                              const float* __restrict__ bias,
                                              const float* __restrict__ gamma,
                                              const float* __restrict__ beta,
                                              const float* __restrict__ mean,
                                              const float* __restrict__ var,
                                              const float* __restrict__ pa,
                                              float* __restrict__ y) {
  int g = blockIdx.x, t = threadIdx.x;
  __shared__ __align__(16) float xs[K1_*NOUT];
  __shared__ float Ash[K1_*K1_];
  __shared__ __align__(16) float sc[NOUT], sh[NOUT];
  if (t < NOUT) {
    float s = gamma[t] * rsqrtf(var[t] + 1e-5f);
    sc[t] = s;
    sh[t] = (bias[t] - mean[t]) * s + beta[t];
  }
  const float* Ag = A2 + (size_t)g * (K1_*K1_);
  for (int i = t; i < K1_*K1_; i += 256) Ash[i] = Ag[i];
  for (int i = t; i < K1_*(NOUT/4); i += 256)
    ((float4*)xs)[i] = ((const float4*)(xw + (size_t)g*K1_*NOUT))[i];
  const float a = pa[0];
  __syncthreads();
  for (int i = t; i < K1_*(NOUT/4); i += 256) {
    int c = i >> 5, fq = i & 31;
    float4 acc = make_float4(0.f, 0.f, 0.f, 0.f);
    for (int j = 0; j < K1_; ++j) {
      float aj = Ash[c*K1_ + j];
      float4 xv = ((const float4*)xs)[j*32 + fq];
      acc.x = fmaf(aj, xv.x, acc.x); acc.y = fmaf(aj, xv.y, acc.y);
      acc.z = fmaf(aj, xv.z, acc.z); acc.w = fmaf(aj, xv.w, acc.w);
    }
    float4 s4 = ((const float4*)sc)[fq];
    float4 h4 = ((const float4*)sh)[fq];
    float4 o;
    o.x = acc.x*s4.x + h4.x; o.y = acc.y*s4.y + h4.y;
    o.z = acc.z*s4.z + h4.z; o.w = acc.w*s4.w + h4.w;
    o.x = o.x >= 0.f ? o.x : a*o.x; o.y = o.y >= 0.f ? o.y : a*o.y;
    o.z = o.z >= 0.f ? o.z : a*o.z; o.w = o.w >= 0.f ? o.w : a*o.w;
    *(float4*)(y + ((size_t)g*K1_ + c)*NOUT + fq*4) = o;
  }
}

// ---------------- score2 ----------------
__global__ __launch_bounds__(256) void score2_k(const float* __restrict__ y2,
                                                const float* __restrict__ As2,
                                                const float* __restrict__ pw,
                                                const float* __restrict__ pb,
                                                float* __restrict__ score) {
  int g = blockIdx.x, t = threadIdx.x;
  __shared__ float sp[K1_];
  int c = t >> 2, q = t & 3;
  float acc = 0.f;
  if (c < K1_) {
    const float* row = y2 + ((size_t)g*K1_ + c) * NOUT;
    for (int f = q*32; f < q*32 + 32; f += 4) {
      float4 v = *(const float4*)(row + f);
      float4 wv = *(const float4*)(pw + f);
      acc += v.x*wv.x + v.y*wv.y + v.z*wv.z + v.w*wv.w;
    }
  }
  acc += __shfl_xor(acc, 1);
  acc += __shfl_xor(acc, 2);
  if (q == 0 && c < K1_) sp[c] = acc;
  __syncthreads();
  if (t < K1_) {
    const float* Ar = As2 + ((size_t)g*K1_ + t) * K1_;
    float s = 0.f;
    for (int j = 0; j < K1_; ++j) s = fmaf(Ar[j], sp[j], s);
    score[g*K1_ + t] = s + pb[0];
  }
}

// ---------------- topk2 + gate + write x and z directly to d_out ----------------
__global__ __launch_bounds__(128) void topk2_out(const float* __restrict__ score,
                                                 const float* __restrict__ y2,
                                                 float* __restrict__ out) {
  int g = blockIdx.x, t = threadIdx.x;  // 128 threads, t == feature index
  __shared__ float s[K1_];
  __shared__ int perm[K2_];
  __shared__ float gate[K2_];
  if (t < K1_) s[t] = score[g*K1_ + t];
  __syncthreads();
  if (t < K1_) {
    float si = s[t];
    int rank = 0;
    for (int j = 0; j < K1_; ++j) {
      float sj = s[j];
      rank += (sj > si) || (sj == si && j < t);
    }
    if (rank < K2_) { perm[rank] = t; gate[rank] = tanhf(si); }
  }
  __syncthreads();
  float zacc = 0.f;
  float* xout = out + (size_t)g * K2_ * NOUT;
  for (int r = 0; r < K2_; ++r) {
    float v = y2[((size_t)g*K1_ + perm[r]) * NOUT + t] * gate[r];
    xout[(size_t)r * NOUT + t] = v;
    zacc += v;
  }
  out[(size_t)G_*K2_*NOUT + (size_t)g*NOUT + t] = zacc * (1.0f / (float)K2_);
}

extern "C" void kernel_launch(void* const* d_in, const int* in_sizes, int n_in,
                              void* d_out, int out_size, void* d_ws, size_t ws_size,
                              hipStream_t stream) {
  const float* h    = (const float*)d_in[0];
  const int*   ei   = (const int*)  d_in[1];
  const float* ew   = (const float*)d_in[2];
  const float* gc1w = (const float*)d_in[3];
  const float* gc1b = (const float*)d_in[4];
  const float* bn1g = (const float*)d_in[5];
  const float* bn1b = (const float*)d_in[6];
  const float* bn1m = (const float*)d_in[7];
  const float* bn1v = (const float*)d_in[8];
  const float* pr1a = (const float*)d_in[9];
  const float* p1w  = (const float*)d_in[10];
  const float* p1b  = (const float*)d_in[11];
  const float* gc2w = (const float*)d_in[12];
  const float* gc2b = (const float*)d_in[13];
  const float* bn2g = (const float*)d_in[14];
  const float* bn2b = (const float*)d_in[15];
  const float* bn2m = (const float*)d_in[16];
  const float* bn2v = (const float*)d_in[17];
  const float* pr2a = (const float*)d_in[18];
  const float* p2w  = (const float*)d_in[19];
  const float* p2b  = (const float*)d_in[20];

  float* w = (float*)d_ws;
  // layout (floats); reuse: xk1 over xw1, xw2 over x0, y2 over y1
  float* A1   = w;                      // 4096
  float* As1  = w + 4096;               // 4096
  float* sc1  = w + 8192;               // 65536
  int*   nidx = (int*)(w + 73728);      // 65536
  float* sc2  = w + 139264;             // 53248
  float* x0   = w + 196608;             // 8388608
  float* xw1  = w + 8585216;            // 16777216
  float* y1   = w + 25362432;           // 16777216
  float* A2   = w + 42139648;           // 2768896
  float* As2  = w + 44908544;           // 2768896  -> end 47677440 floats (~182 MiB)
  float* xk1  = xw1;
  float* xw2  = x0;
  float* y2   = y1;

  transpose_h<<<dim3(B_*C_, F_/32), dim3(32, 8), 0, stream>>>(h, x0);
  build_A1<<<1, 256, 0, stream>>>(ei, ew, A1, As1);
  gemm_t<128,128,8,8><<<dim3(N1_/128, NHID/128), 256, 0, stream>>>(x0, gc1w, xw1, N1_, NHID, F_);
  agg1_k<<<G_, 256, 0, stream>>>(xw1, A1, gc1b, bn1g, bn1b, bn1m, bn1v, pr1a, y1);
  score1_k<<<G_, 256, 0, stream>>>(y1, As1, p1w, p1b, sc1);
  topk1_gate<<<G_, 256, 0, stream>>>(sc1, y1, xk1, nidx);
  build_A2<<<G_, 256, 0, stream>>>(ei, ew, nidx, A2, As2);
  gemm_t<128,64,8,4><<<dim3(N2_/128, NOUT/64), 256, 0, stream>>>(xk1, gc2w, xw2, N2_, NOUT, NHID);
  agg2_k<<<G_, 256, 0, stream>>>(xw2, A2, gc2b, bn2g, bn2b, bn2m, bn2v, pr2a, y2);
  score2_k<<<G_, 256, 0, stream>>>(y2, As2, p2w, p2b, sc2);
  topk2_out<<<G_, 128, 0, stream>>>(sc2, y2, (float*)d_out);
}

// Round 4
// 204.730 us; speedup vs baseline: 2.5517x; 1.5058x over previous
//
#include <hip/hip_runtime.h>
#include <math.h>

#define B_   32
#define C_   64
#define F_   128
#define TP_  32
#define G_   (B_*TP_)      // 1024 graphs
#define NHID 256
#define NOUT 128
#define E_   512
#define K1_  52            // ceil(0.8*64)
#define K2_  42            // ceil(0.8*52)
#define N2_  (G_*K1_)      // 53248 rows layer 2

// -------- build shared 64x64 A1 (edge-weight norm) and As1 (binary norm) -------------
__global__ __launch_bounds__(256) void build_A1(const int* __restrict__ ei,
                                                const float* __restrict__ ew,
                                                float* __restrict__ A1,
                                                float* __restrict__ As1) {
  __shared__ float A1s[C_*C_], As1s[C_*C_];
  __shared__ float dg[C_], dgs[C_], dis[C_], diss[C_];
  int t = threadIdx.x;
  for (int i = t; i < C_*C_; i += 256) { A1s[i] = 0.f; As1s[i] = 0.f; }
  if (t < C_) { dg[t] = 1.f; dgs[t] = 1.f; }   // self-loop weight 1
  int r0[2], c0[2]; float w0[2];
#pragma unroll
  for (int p = 0; p < 2; ++p) {
    int e = t + p*256;
    r0[p] = ei[e]; c0[p] = ei[E_ + e]; w0[p] = ew[e];
  }
  __syncthreads();
#pragma unroll
  for (int p = 0; p < 2; ++p) {
    atomicAdd(&dg[c0[p]], w0[p]);
    atomicAdd(&dgs[c0[p]], 1.f);
  }
  __syncthreads();
  if (t < C_) { dis[t] = rsqrtf(dg[t]); diss[t] = rsqrtf(dgs[t]); }
  __syncthreads();
#pragma unroll
  for (int p = 0; p < 2; ++p) {
    int r = r0[p], c = c0[p];
    atomicAdd(&A1s[c*C_ + r],  dis[r] * w0[p] * dis[c]);
    atomicAdd(&As1s[c*C_ + r], diss[r] * diss[c]);
  }
  if (t < C_) {
    atomicAdd(&A1s[t*C_ + t],  dis[t] * dis[t]);
    atomicAdd(&As1s[t*C_ + t], diss[t] * diss[t]);
  }
  __syncthreads();
  for (int i = t; i < C_*C_; i += 256) { A1[i] = A1s[i]; As1[i] = As1s[i]; }
}

// ---- preagg: xa2[b,c,f,tp] = sum_j A1[c,j] * h[b,j,f,tp]  (per-b, (f,tp) cols) ------
__global__ __launch_bounds__(256) void preagg_b(const float* __restrict__ h,
                                                const float* __restrict__ A1,
                                                float* __restrict__ xa2) {
  int bid = blockIdx.x; int b = bid >> 5, q = bid & 31;   // q: 128-col chunk of 4096
  __shared__ float At[64*68];                              // A1 transposed [j][c]
  __shared__ __align__(16) float Hs[64*132];
  int t = threadIdx.x;
#pragma unroll
  for (int p = 0; p < 16; ++p) {
    int m = t + p*256;                      // A1[c*64+j]
    At[(m & 63)*68 + (m >> 6)] = A1[m];
  }
  const float* hb = h + ((size_t)b*64)*4096 + q*128;
#pragma unroll
  for (int p = 0; p < 8; ++p) {
    int idx = t + p*256;                    // 2048 float4 tiles: 64 j x 32 f4
    int j = idx >> 5, f4 = idx & 31;
    *(float4*)&Hs[j*132 + f4*4] = *(const float4*)(hb + (size_t)j*4096 + f4*4);
  }
  __syncthreads();
  int tx = t & 31, ty = t >> 5;             // tx: f4 col, ty: 8-row c block
  float acc[8][4] = {};
  for (int j = 0; j < 64; ++j) {
    float a[8];
    *(float4*)&a[0] = *(const float4*)&At[j*68 + ty*8];
    *(float4*)&a[4] = *(const float4*)&At[j*68 + ty*8 + 4];
    float4 hv = *(const float4*)&Hs[j*132 + tx*4];
#pragma unroll
    for (int i = 0; i < 8; ++i) {
      acc[i][0] = fmaf(a[i], hv.x, acc[i][0]);
      acc[i][1] = fmaf(a[i], hv.y, acc[i][1]);
      acc[i][2] = fmaf(a[i], hv.z, acc[i][2]);
      acc[i][3] = fmaf(a[i], hv.w, acc[i][3]);
    }
  }
  float* outp = xa2 + (((size_t)b*64) << 12) + q*128 + tx*4;
#pragma unroll
  for (int i = 0; i < 8; ++i) {
    int c = ty*8 + i;
    *(float4*)(outp + ((size_t)c << 12)) =
        make_float4(acc[i][0], acc[i][1], acc[i][2], acc[i][3]);
  }
}

// ---- gemm1e: y1 = prelu(bn(xa @ W1 + b1)); also per-row partial pool1 dots ----------
// A rows are (b, c, tp): block covers b fixed, c0..c0+3, all 32 tp  (128 rows)
__global__ __launch_bounds__(256) void gemm1e(const float* __restrict__ xa2,
                                              const float* __restrict__ W1,
                                              const float* __restrict__ gc1b,
                                              const float* __restrict__ g1,
                                              const float* __restrict__ be1,
                                              const float* __restrict__ mu1,
                                              const float* __restrict__ v1,
                                              const float* __restrict__ pa1,
                                              const float* __restrict__ pw1,
                                              float* __restrict__ y1,
                                              float* __restrict__ dots2) {
  __shared__ __align__(16) float As[16*132];
  __shared__ __align__(16) float Bs[16*132];
  int t = threadIdx.x;
  int mb = blockIdx.x; int b = mb >> 4, c0 = (mb & 15) * 4;
  int nb = blockIdx.y; int col0 = nb * 128;
  int tx = t & 15, ty = t >> 4;
  float4 scv[2], shv[2], pwv[2];
#pragma unroll
  for (int jh = 0; jh < 2; ++jh) {
    int col = col0 + jh*64 + 4*tx;
    float4 gv = *(const float4*)(g1 + col);
    float4 vv = *(const float4*)(v1 + col);
    float4 bv = *(const float4*)(be1 + col);
    float4 mv = *(const float4*)(mu1 + col);
    float4 b0 = *(const float4*)(gc1b + col);
    float4 s;
    s.x = gv.x * rsqrtf(vv.x + 1e-5f); s.y = gv.y * rsqrtf(vv.y + 1e-5f);
    s.z = gv.z * rsqrtf(vv.z + 1e-5f); s.w = gv.w * rsqrtf(vv.w + 1e-5f);
    scv[jh] = s;
    shv[jh] = make_float4((b0.x - mv.x)*s.x + bv.x, (b0.y - mv.y)*s.y + bv.y,
                          (b0.z - mv.z)*s.z + bv.z, (b0.w - mv.w)*s.w + bv.w);
    pwv[jh] = *(const float4*)(pw1 + col);
  }
  float a1v = pa1[0];
  float acc[8][8] = {};
  const float* abase = xa2 + (((size_t)(b*64 + c0)) << 12);
  for (int k0 = 0; k0 < 128; k0 += 16) {
#pragma unroll
    for (int p = 0; p < 2; ++p) {
      int idx = t + p*256; int ci = idx >> 7, rem = idx & 127;
      float4 av = *(const float4*)(abase + ((size_t)ci << 12) + k0*32 + rem*4);
      int kl = rem >> 3, tp0 = (rem & 7)*4;
      *(float4*)&As[kl*132 + ci*32 + tp0] = av;
    }
#pragma unroll
    for (int p = 0; p < 2; ++p) {
      int rk = (t >> 5) + p*8, cn = (t & 31)*4;
      *(float4*)&Bs[rk*132 + cn] = *(const float4*)(W1 + (size_t)(k0+rk)*NHID + col0 + cn);
    }
    __syncthreads();
#pragma unroll
    for (int kk = 0; kk < 16; ++kk) {
      float a[8], bb[8];
      *(float4*)&a[0]  = *(const float4*)&As[kk*132 + 4*ty];
      *(float4*)&a[4]  = *(const float4*)&As[kk*132 + 64 + 4*ty];
      *(float4*)&bb[0] = *(const float4*)&Bs[kk*132 + 4*tx];
      *(float4*)&bb[4] = *(const float4*)&Bs[kk*132 + 64 + 4*tx];
#pragma unroll
      for (int i = 0; i < 8; ++i)
#pragma unroll
        for (int j = 0; j < 8; ++j)
          acc[i][j] = fmaf(a[i], bb[j], acc[i][j]);
    }
    __syncthreads();
  }
#pragma unroll
  for (int ih = 0; ih < 2; ++ih)
#pragma unroll
    for (int i = 0; i < 4; ++i) {
      int r = ih*64 + 4*ty + i;
      int cl = r >> 5, tp = r & 31;
      size_t R = (size_t)(b*32 + tp)*64 + c0 + cl;
      float dpart = 0.f;
#pragma unroll
      for (int jh = 0; jh < 2; ++jh) {
        float4 o;
        o.x = acc[ih*4+i][jh*4+0]*scv[jh].x + shv[jh].x;
        o.y = acc[ih*4+i][jh*4+1]*scv[jh].y + shv[jh].y;
        o.z = acc[ih*4+i][jh*4+2]*scv[jh].z + shv[jh].z;
        o.w = acc[ih*4+i][jh*4+3]*scv[jh].w + shv[jh].w;
        o.x = o.x >= 0.f ? o.x : a1v*o.x; o.y = o.y >= 0.f ? o.y : a1v*o.y;
        o.z = o.z >= 0.f ? o.z : a1v*o.z; o.w = o.w >= 0.f ? o.w : a1v*o.w;
        *(float4*)(y1 + R*NHID + col0 + jh*64 + 4*tx) = o;
        dpart += o.x*pwv[jh].x + o.y*pwv[jh].y + o.z*pwv[jh].z + o.w*pwv[jh].w;
      }
      dpart += __shfl_xor(dpart, 1);
      dpart += __shfl_xor(dpart, 2);
      dpart += __shfl_xor(dpart, 4);
      dpart += __shfl_xor(dpart, 8);
      if (tx == 0) dots2[R*2 + nb] = dpart;
    }
}

// ---- pool1: scores = As1 @ dots + b; stable top-52; gate; gather y1 -> xk1 ----------
__global__ __launch_bounds__(256) void pool1_k(const float* __restrict__ dots2,
                                               const float* __restrict__ As1,
                                               const float* __restrict__ p1b,
                                               const float* __restrict__ y1,
                                               float* __restrict__ xk1,
                                               int* __restrict__ nidx) {
  int g = blockIdx.x, t = threadIdx.x;
  __shared__ float As1s[64*65];
  __shared__ float sp[64], s[64];
  __shared__ int perm[K1_];
  __shared__ float gate[K1_];
  for (int i = t; i < 4096; i += 256)
    As1s[(i >> 6)*65 + (i & 63)] = As1[i];
  if (t < 64) sp[t] = dots2[(g*64 + t)*2] + dots2[(g*64 + t)*2 + 1];
  __syncthreads();
  if (t < 64) {
    float acc = p1b[0];
    for (int j = 0; j < 64; ++j) acc = fmaf(As1s[t*65 + j], sp[j], acc);
    s[t] = acc;
  }
  __syncthreads();
  if (t < 64) {
    float si = s[t];
    int rank = 0;
    for (int j = 0; j < 64; ++j) {
      float sj = s[j];
      rank += (sj > si) || (sj == si && j < t);
    }
    nidx[g*64 + t] = (rank < K1_) ? rank : -1;
    if (rank < K1_) { perm[rank] = t; gate[rank] = tanhf(si); }
  }
  __syncthreads();
  for (int p = 0; p < 13; ++p) {
    int idx = t + p*256;
    if (idx < K1_*64) {
      int r = idx >> 6, q = idx & 63;
      float4 v = *(const float4*)(y1 + ((size_t)g*64 + perm[r])*NHID + q*4);
      float gt = gate[r];
      v.x *= gt; v.y *= gt; v.z *= gt; v.w *= gt;
      *(float4*)(xk1 + ((size_t)g*K1_ + r)*NHID + q*4) = v;
    }
  }
}

// ---------------- generic f32 GEMM (round-2 verified) --------------------------------
template<int BM, int BN, int TM, int TN>
__global__ __launch_bounds__(256) void gemm_t(const float* __restrict__ A,
                                              const float* __restrict__ Bm,
                                              float* __restrict__ Cm,
                                              int M, int N, int K) {
  constexpr int BK = 16;
  __shared__ __align__(16) float As[BK][BM + 4];
  __shared__ __align__(16) float Bs[BK][BN + 4];
  int t = threadIdx.x;
  int row0 = blockIdx.x * BM, col0 = blockIdx.y * BN;
  constexpr int TX = BN / TN;
  int tx = t % TX, ty = t / TX;
  float acc[TM][TN] = {};
  for (int k0 = 0; k0 < K; k0 += BK) {
#pragma unroll
    for (int p = 0; p < BM/64; ++p) {
      int rm = (t >> 2) + p*64, tq = t & 3;
      float4 av = *(const float4*)(A + (size_t)(row0 + rm) * K + k0 + 4*tq);
      As[4*tq+0][rm] = av.x; As[4*tq+1][rm] = av.y;
      As[4*tq+2][rm] = av.z; As[4*tq+3][rm] = av.w;
    }
#pragma unroll
    for (int p = 0; p < BK*BN/1024; ++p) {
      int rk = t / (BN/4) + p * (1024/BN);
      int cn = (t % (BN/4)) * 4;
      *(float4*)&Bs[rk][cn] = *(const float4*)(Bm + (size_t)(k0 + rk) * N + col0 + cn);
    }
    __syncthreads();
#pragma unroll
    for (int kk = 0; kk < BK; ++kk) {
      float a[TM], b[TN];
      *(float4*)&a[0] = *(const float4*)&As[kk][4*ty];
      if (TM == 8) *(float4*)&a[4] = *(const float4*)&As[kk][BM/2 + 4*ty];
      *(float4*)&b[0] = *(const float4*)&Bs[kk][4*tx];
      if (TN == 8) *(float4*)&b[4] = *(const float4*)&Bs[kk][BN/2 + 4*tx];
#pragma unroll
      for (int i = 0; i < TM; ++i)
#pragma unroll
        for (int j = 0; j < TN; ++j)
          acc[i][j] = fmaf(a[i], b[j], acc[i][j]);
    }
    __syncthreads();
  }
#pragma unroll
  for (int ih = 0; ih < TM/4; ++ih)
#pragma unroll
    for (int i = 0; i < 4; ++i) {
      int r = row0 + ih*(BM/2) + 4*ty + i;
#pragma unroll
      for (int jh = 0; jh < TN/4; ++jh) {
        float4 v = make_float4(acc[ih*4+i][jh*4+0], acc[ih*4+i][jh*4+1],
                               acc[ih*4+i][jh*4+2], acc[ih*4+i][jh*4+3]);
        *(float4*)(Cm + (size_t)r * N + col0 + jh*(BN/2) + 4*tx) = v;
      }
    }
}

// ---- mega2: build A2/As2 (LDS) + agg+BN+PReLU + in-reg dots + scores + topk + out ---
__global__ __launch_bounds__(256) void mega2(const int* __restrict__ ei,
                                             const float* __restrict__ ew,
                                             const int* __restrict__ nidx,
                                             const float* __restrict__ xw2,
                                             const float* __restrict__ gc2b,
                                             const float* __restrict__ g2,
                                             const float* __restrict__ be2,
                                             const float* __restrict__ mu2,
                                             const float* __restrict__ v2,
                                             const float* __restrict__ pa2,
                                             const float* __restrict__ pw2,
                                             const float* __restrict__ p2b,
                                             float* __restrict__ y2,
                                             float* __restrict__ out) {
  int g = blockIdx.x, t = threadIdx.x;
  __shared__ float A2t[64*68];                 // [j][c] zero-padded to 64 rows/cols
  __shared__ float As2s[K1_*K1_];
  __shared__ __align__(16) float xs[K1_*132];
  __shared__ float dg[K1_], dgs[K1_], dis[K1_], diss[K1_], d[K1_], s[K1_];
  __shared__ int nm[C_], perm[K2_];
  __shared__ float gate[K2_];
  __shared__ float4 zpart[8][32];

  for (int i = t; i < 64*68; i += 256) A2t[i] = 0.f;
  for (int i = t; i < K1_*K1_; i += 256) As2s[i] = 0.f;
  if (t < C_) nm[t] = nidx[g*C_ + t];
  if (t < K1_) { dg[t] = 1.f; dgs[t] = 1.f; }
  for (int p = 0; p < 7; ++p) {
    int idx = t + p*256;
    if (idx < K1_*32) {
      int r = idx >> 5, f4 = idx & 31;
      *(float4*)&xs[r*132 + f4*4] =
          *(const float4*)(xw2 + ((size_t)g*K1_ + r)*NOUT + f4*4);
    }
  }
  int eR[2], eC[2]; float eW[2];
#pragma unroll
  for (int p = 0; p < 2; ++p) {
    int e = t + p*256;
    eR[p] = ei[e]; eC[p] = ei[E_ + e]; eW[p] = ew[e];
  }
  __syncthreads();
  int nr[2], nc[2]; bool val[2];
#pragma unroll
  for (int p = 0; p < 2; ++p) {
    nr[p] = nm[eR[p]]; nc[p] = nm[eC[p]];
    val[p] = (nr[p] >= 0) && (nc[p] >= 0);
    if (val[p]) { atomicAdd(&dg[nc[p]], eW[p]); atomicAdd(&dgs[nc[p]], 1.f); }
  }
  __syncthreads();
  if (t < K1_) { dis[t] = rsqrtf(dg[t]); diss[t] = rsqrtf(dgs[t]); }
  __syncthreads();
#pragma unroll
  for (int p = 0; p < 2; ++p) {
    if (val[p]) {
      atomicAdd(&A2t[nr[p]*68 + nc[p]],  dis[nr[p]] * eW[p] * dis[nc[p]]);
      atomicAdd(&As2s[nc[p]*K1_ + nr[p]], diss[nr[p]] * diss[nc[p]]);
    }
  }
  if (t < K1_) {
    atomicAdd(&A2t[t*68 + t],     dis[t]*dis[t]);
    atomicAdd(&As2s[t*K1_ + t],   diss[t]*diss[t]);
  }
  __syncthreads();
  // agg phase: rows c = ty*8+i (c<52 real), cols 4*tx
  int tx = t & 31, ty = t >> 5;
  float4 scv, shv, pwv;
  {
    int col = 4*tx;
    float4 gv = *(const float4*)(g2 + col);
    float4 vv = *(const float4*)(v2 + col);
    float4 bv = *(const float4*)(be2 + col);
    float4 mv = *(const float4*)(mu2 + col);
    float4 b0 = *(const float4*)(gc2b + col);
    scv.x = gv.x * rsqrtf(vv.x + 1e-5f); scv.y = gv.y * rsqrtf(vv.y + 1e-5f);
    scv.z = gv.z * rsqrtf(vv.z + 1e-5f); scv.w = gv.w * rsqrtf(vv.w + 1e-5f);
    shv = make_float4((b0.x - mv.x)*scv.x + bv.x, (b0.y - mv.y)*scv.y + bv.y,
                      (b0.z - mv.z)*scv.z + bv.z, (b0.w - mv.w)*scv.w + bv.w);
    pwv = *(const float4*)(pw2 + col);
  }
  float a2v = pa2[0];
  float acc[8][4] = {};
  for (int j = 0; j < K1_; ++j) {
    float a[8];
    *(float4*)&a[0] = *(const float4*)&A2t[j*68 + ty*8];
    *(float4*)&a[4] = *(const float4*)&A2t[j*68 + ty*8 + 4];
    float4 xv = *(const float4*)&xs[j*132 + tx*4];
#pragma unroll
    for (int i = 0; i < 8; ++i) {
      acc[i][0] = fmaf(a[i], xv.x, acc[i][0]);
      acc[i][1] = fmaf(a[i], xv.y, acc[i][1]);
      acc[i][2] = fmaf(a[i], xv.z, acc[i][2]);
      acc[i][3] = fmaf(a[i], xv.w, acc[i][3]);
    }
  }
#pragma unroll
  for (int i = 0; i < 8; ++i) {
    int c = ty*8 + i;
    if (c < K1_) {
      float4 o;
      o.x = acc[i][0]*scv.x + shv.x; o.y = acc[i][1]*scv.y + shv.y;
      o.z = acc[i][2]*scv.z + shv.z; o.w = acc[i][3]*scv.w + shv.w;
      o.x = o.x >= 0.f ? o.x : a2v*o.x; o.y = o.y >= 0.f ? o.y : a2v*o.y;
      o.z = o.z >= 0.f ? o.z : a2v*o.z; o.w = o.w >= 0.f ? o.w : a2v*o.w;
      *(float4*)(y2 + ((size_t)g*K1_ + c)*NOUT + 4*tx) = o;
      float dp = o.x*pwv.x + o.y*pwv.y + o.z*pwv.z + o.w*pwv.w;
      dp += __shfl_xor(dp, 1);
      dp += __shfl_xor(dp, 2);
      dp += __shfl_xor(dp, 4);
      dp += __shfl_xor(dp, 8);
      dp += __shfl_xor(dp, 16);
      if (tx == 0) d[c] = dp;
    }
  }
  __syncthreads();
  if (t < K1_) {
    float sv = p2b[0];
    for (int j = 0; j < K1_; ++j) sv = fmaf(As2s[t*K1_ + j], d[j], sv);
    s[t] = sv;
  }
  __syncthreads();
  if (t < K1_) {
    float si = s[t];
    int rank = 0;
    for (int j = 0; j < K1_; ++j) {
      float sj = s[j];
      rank += (sj > si) || (sj == si && j < t);
    }
    if (rank < K2_) { perm[rank] = t; gate[rank] = tanhf(si); }
  }
  __syncthreads();
  float4 zp = make_float4(0.f, 0.f, 0.f, 0.f);
  for (int p = 0; p < 6; ++p) {
    int idx = t + p*256;
    if (idx < K2_*32) {
      int r = idx >> 5, f4 = idx & 31;        // f4 == tx (constant per thread)
      float4 v = *(const float4*)(y2 + ((size_t)g*K1_ + perm[r])*NOUT + f4*4);
      float gt = gate[r];
      v.x *= gt; v.y *= gt; v.z *= gt; v.w *= gt;
      *(float4*)(out + ((size_t)g*K2_ + r)*NOUT + f4*4) = v;
      zp.x += v.x; zp.y += v.y; zp.z += v.z; zp.w += v.w;
    }
  }
  zpart[ty][tx] = zp;
  __syncthreads();
  if (t < 32) {
    float4 z = make_float4(0.f, 0.f, 0.f, 0.f);
#pragma unroll
    for (int k = 0; k < 8; ++k) {
      float4 v = zpart[k][t];
      z.x += v.x; z.y += v.y; z.z += v.z; z.w += v.w;
    }
    const float inv = 1.0f / (float)K2_;
    z.x *= inv; z.y *= inv; z.z *= inv; z.w *= inv;
    *(float4*)(out + (size_t)G_*K2_*NOUT + (size_t)g*NOUT + 4*t) = z;
  }
}

extern "C" void kernel_launch(void* const* d_in, const int* in_sizes, int n_in,
                              void* d_out, int out_size, void* d_ws, size_t ws_size,
                              hipStream_t stream) {
  const float* h    = (const float*)d_in[0];
  const int*   ei   = (const int*)  d_in[1];
  const float* ew   = (const float*)d_in[2];
  const float* gc1w = (const float*)d_in[3];
  const float* gc1b = (const float*)d_in[4];
  const float* bn1g = (const float*)d_in[5];
  const float* bn1b = (const float*)d_in[6];
  const float* bn1m = (const float*)d_in[7];
  const float* bn1v = (const float*)d_in[8];
  const float* pr1a = (const float*)d_in[9];
  const float* p1w  = (const float*)d_in[10];
  const float* p1b  = (const float*)d_in[11];
  const float* gc2w = (const float*)d_in[12];
  const float* gc2b = (const float*)d_in[13];
  const float* bn2g = (const float*)d_in[14];
  const float* bn2b = (const float*)d_in[15];
  const float* bn2m = (const float*)d_in[16];
  const float* bn2v = (const float*)d_in[17];
  const float* pr2a = (const float*)d_in[18];
  const float* p2w  = (const float*)d_in[19];
  const float* p2b  = (const float*)d_in[20];

  float* w = (float*)d_ws;
  // float offsets
  float* A1    = w;                       // 4096
  float* As1   = w + 4096;                // 4096
  float* dots2 = w + 8192;                // 131072 (65536 rows x 2)
  int*   nidx  = (int*)(w + 139264);      // 65536
  float* xa2   = w + 262144;              // 8388608  (32*64*128*32)
  float* y1    = w + 8650752;             // 16777216 (65536*256)
  float* xk1   = w + 25427968;            // 13631488 (53248*256)  end: 39059456 fl
  float* xw2   = xa2;                     // 6815744 <= 8388608 (xa2 dead after gemm1e)
  float* y2    = y1;                      // 6815744 <= 16777216 (y1 dead after pool1)

  build_A1<<<1, 256, 0, stream>>>(ei, ew, A1, As1);
  preagg_b<<<1024, 256, 0, stream>>>(h, A1, xa2);
  gemm1e<<<dim3(512, 2), 256, 0, stream>>>(xa2, gc1w, gc1b, bn1g, bn1b, bn1m, bn1v,
                                           pr1a, p1w, y1, dots2);
  pool1_k<<<G_, 256, 0, stream>>>(dots2, As1, p1b, y1, xk1, nidx);
  gemm_t<128,64,8,4><<<dim3(N2_/128, NOUT/64), 256, 0, stream>>>(xk1, gc2w, xw2,
                                                                 N2_, NOUT, NHID);
  mega2<<<G_, 256, 0, stream>>>(ei, ew, nidx, xw2, gc2b, bn2g, bn2b, bn2m, bn2v,
                                pr2a, p2w, p2b, y2, (float*)d_out);
}

// Round 5
// 190.588 us; speedup vs baseline: 2.7410x; 1.0742x over previous
//
#include <hip/hip_runtime.h>
#include <math.h>

#define B_   32
#define C_   64
#define F_   128
#define TP_  32
#define G_   (B_*TP_)      // 1024 graphs
#define NHID 256
#define NOUT 128
#define E_   512
#define K1_  52            // ceil(0.8*64)
#define K2_  42            // ceil(0.8*52)
#define N2_  (G_*K1_)      // 53248 rows layer 2

// -------- build shared 64x64 A1 (edge-weight norm) and As1 (binary norm) -------------
__global__ __launch_bounds__(256) void build_A1(const int* __restrict__ ei,
                                                const float* __restrict__ ew,
                                                float* __restrict__ A1,
                                                float* __restrict__ As1) {
  __shared__ float A1s[C_*C_], As1s[C_*C_];
  __shared__ float dg[C_], dgs[C_], dis[C_], diss[C_];
  int t = threadIdx.x;
  for (int i = t; i < C_*C_; i += 256) { A1s[i] = 0.f; As1s[i] = 0.f; }
  if (t < C_) { dg[t] = 1.f; dgs[t] = 1.f; }   // self-loop weight 1
  int r0[2], c0[2]; float w0[2];
#pragma unroll
  for (int p = 0; p < 2; ++p) {
    int e = t + p*256;
    r0[p] = ei[e]; c0[p] = ei[E_ + e]; w0[p] = ew[e];
  }
  __syncthreads();
#pragma unroll
  for (int p = 0; p < 2; ++p) {
    atomicAdd(&dg[c0[p]], w0[p]);
    atomicAdd(&dgs[c0[p]], 1.f);
  }
  __syncthreads();
  if (t < C_) { dis[t] = rsqrtf(dg[t]); diss[t] = rsqrtf(dgs[t]); }
  __syncthreads();
#pragma unroll
  for (int p = 0; p < 2; ++p) {
    int r = r0[p], c = c0[p];
    atomicAdd(&A1s[c*C_ + r],  dis[r] * w0[p] * dis[c]);
    atomicAdd(&As1s[c*C_ + r], diss[r] * diss[c]);
  }
  if (t < C_) {
    atomicAdd(&A1s[t*C_ + t],  dis[t] * dis[t]);
    atomicAdd(&As1s[t*C_ + t], diss[t] * diss[t]);
  }
  __syncthreads();
  for (int i = t; i < C_*C_; i += 256) { A1[i] = A1s[i]; As1[i] = As1s[i]; }
}

// ---- preagg: xa2[b,c,f,tp] = sum_j A1[c,j] * h[b,j,f,tp]  (per-b, (f,tp) cols) ------
__global__ __launch_bounds__(256) void preagg_b(const float* __restrict__ h,
                                                const float* __restrict__ A1,
                                                float* __restrict__ xa2) {
  int bid = blockIdx.x; int b = bid >> 5, q = bid & 31;   // q: 128-col chunk of 4096
  __shared__ float At[64*68];                              // A1 transposed [j][c]
  __shared__ __align__(16) float Hs[64*132];
  int t = threadIdx.x;
#pragma unroll
  for (int p = 0; p < 16; ++p) {
    int m = t + p*256;                      // A1[c*64+j]
    At[(m & 63)*68 + (m >> 6)] = A1[m];
  }
  const float* hb = h + ((size_t)b*64)*4096 + q*128;
#pragma unroll
  for (int p = 0; p < 8; ++p) {
    int idx = t + p*256;                    // 2048 float4 tiles: 64 j x 32 f4
    int j = idx >> 5, f4 = idx & 31;
    *(float4*)&Hs[j*132 + f4*4] = *(const float4*)(hb + (size_t)j*4096 + f4*4);
  }
  __syncthreads();
  int tx = t & 31, ty = t >> 5;             // tx: f4 col, ty: 8-row c block
  float acc[8][4] = {};
  for (int j = 0; j < 64; ++j) {
    float a[8];
    *(float4*)&a[0] = *(const float4*)&At[j*68 + ty*8];
    *(float4*)&a[4] = *(const float4*)&At[j*68 + ty*8 + 4];
    float4 hv = *(const float4*)&Hs[j*132 + tx*4];
#pragma unroll
    for (int i = 0; i < 8; ++i) {
      acc[i][0] = fmaf(a[i], hv.x, acc[i][0]);
      acc[i][1] = fmaf(a[i], hv.y, acc[i][1]);
      acc[i][2] = fmaf(a[i], hv.z, acc[i][2]);
      acc[i][3] = fmaf(a[i], hv.w, acc[i][3]);
    }
  }
  float* outp = xa2 + (((size_t)b*64) << 12) + q*128 + tx*4;
#pragma unroll
  for (int i = 0; i < 8; ++i) {
    int c = ty*8 + i;
    *(float4*)(outp + ((size_t)c << 12)) =
        make_float4(acc[i][0], acc[i][1], acc[i][2], acc[i][3]);
  }
}

// ---- gemm1e: y1 = prelu(bn(xa @ W1 + b1)); per-row partial pool1 dots ---------------
// block: b fixed, 8 c's x 32 tp = 256 rows; 128 cols; 16x8 microtile
__global__ __launch_bounds__(256) void gemm1e(const float* __restrict__ xa2,
                                              const float* __restrict__ W1,
                                              const float* __restrict__ gc1b,
                                              const float* __restrict__ g1,
                                              const float* __restrict__ be1,
                                              const float* __restrict__ mu1,
                                              const float* __restrict__ v1,
                                              const float* __restrict__ pa1,
                                              const float* __restrict__ pw1,
                                              float* __restrict__ y1,
                                              float* __restrict__ dots2) {
  __shared__ __align__(16) float As[16*260];   // [k][row], row = c_local*32+tp
  __shared__ __align__(16) float Bs[16*132];   // [k][col]
  int t = threadIdx.x;
  int mb = blockIdx.x; int b = mb >> 3, c0 = (mb & 7) * 8;
  int nb = blockIdx.y; int col0 = nb * 128;
  int tx = t & 15, ty = t >> 4;                // ty in 0..15
  float acc[16][8] = {};
  const float* abase = xa2 + (((size_t)(b*64 + c0)) << 12);
  for (int k0 = 0; k0 < 128; k0 += 16) {
#pragma unroll
    for (int p = 0; p < 4; ++p) {              // 1024 float4: 16 k x 64 row4
      int idx = t + p*256;
      int kl = idx >> 6, rr4 = idx & 63;
      int cl = rr4 >> 3, tp0 = (rr4 & 7)*4;
      float4 av = *(const float4*)(abase + ((size_t)cl << 12) + (k0 + kl)*32 + tp0);
      *(float4*)&As[kl*260 + rr4*4] = av;
    }
#pragma unroll
    for (int p = 0; p < 2; ++p) {              // 512 float4: 16 k x 32 col4
      int idx = t + p*256;
      int rk = idx >> 5, cn = (idx & 31)*4;
      *(float4*)&Bs[rk*132 + cn] = *(const float4*)(W1 + (size_t)(k0+rk)*NHID + col0 + cn);
    }
    __syncthreads();
#pragma unroll
    for (int kk = 0; kk < 16; ++kk) {
      float a[16], bb[8];
#pragma unroll
      for (int qd = 0; qd < 4; ++qd)
        *(float4*)&a[4*qd] = *(const float4*)&As[kk*260 + qd*64 + 4*ty];
      *(float4*)&bb[0] = *(const float4*)&Bs[kk*132 + 4*tx];
      *(float4*)&bb[4] = *(const float4*)&Bs[kk*132 + 64 + 4*tx];
#pragma unroll
      for (int i = 0; i < 16; ++i)
#pragma unroll
        for (int j = 0; j < 8; ++j)
          acc[i][j] = fmaf(a[i], bb[j], acc[i][j]);
    }
    __syncthreads();
  }
  // epilogue constants (computed late to keep loop VGPR pressure low)
  float4 scv[2], shv[2], pwv[2];
#pragma unroll
  for (int jh = 0; jh < 2; ++jh) {
    int col = col0 + jh*64 + 4*tx;
    float4 gv = *(const float4*)(g1 + col);
    float4 vv = *(const float4*)(v1 + col);
    float4 bv = *(const float4*)(be1 + col);
    float4 mv = *(const float4*)(mu1 + col);
    float4 b0 = *(const float4*)(gc1b + col);
    float4 s;
    s.x = gv.x * rsqrtf(vv.x + 1e-5f); s.y = gv.y * rsqrtf(vv.y + 1e-5f);
    s.z = gv.z * rsqrtf(vv.z + 1e-5f); s.w = gv.w * rsqrtf(vv.w + 1e-5f);
    scv[jh] = s;
    shv[jh] = make_float4((b0.x - mv.x)*s.x + bv.x, (b0.y - mv.y)*s.y + bv.y,
                          (b0.z - mv.z)*s.z + bv.z, (b0.w - mv.w)*s.w + bv.w);
    pwv[jh] = *(const float4*)(pw1 + col);
  }
  float a1v = pa1[0];
#pragma unroll
  for (int qd = 0; qd < 4; ++qd)
#pragma unroll
    for (int i = 0; i < 4; ++i) {
      int rr = qd*64 + 4*ty + i;
      int cl = rr >> 5, tp = rr & 31;
      size_t R = (size_t)(b*32 + tp)*64 + c0 + cl;
      float dpart = 0.f;
#pragma unroll
      for (int jh = 0; jh < 2; ++jh) {
        float4 o;
        o.x = acc[qd*4+i][jh*4+0]*scv[jh].x + shv[jh].x;
        o.y = acc[qd*4+i][jh*4+1]*scv[jh].y + shv[jh].y;
        o.z = acc[qd*4+i][jh*4+2]*scv[jh].z + shv[jh].z;
        o.w = acc[qd*4+i][jh*4+3]*scv[jh].w + shv[jh].w;
        o.x = o.x >= 0.f ? o.x : a1v*o.x; o.y = o.y >= 0.f ? o.y : a1v*o.y;
        o.z = o.z >= 0.f ? o.z : a1v*o.z; o.w = o.w >= 0.f ? o.w : a1v*o.w;
        *(float4*)(y1 + R*NHID + col0 + jh*64 + 4*tx) = o;
        dpart += o.x*pwv[jh].x + o.y*pwv[jh].y + o.z*pwv[jh].z + o.w*pwv[jh].w;
      }
      dpart += __shfl_xor(dpart, 1);
      dpart += __shfl_xor(dpart, 2);
      dpart += __shfl_xor(dpart, 4);
      dpart += __shfl_xor(dpart, 8);
      if (tx == 0) dots2[R*2 + nb] = dpart;
    }
}

// ---- pool1s: scores = As1 @ dots + b; stable top-52; emit rowsrc/rowgate/nidx -------
__global__ __launch_bounds__(256) void pool1s(const float* __restrict__ dots2,
                                              const float* __restrict__ As1,
                                              const float* __restrict__ p1b,
                                              int* __restrict__ rowsrc,
                                              float* __restrict__ rowgate,
                                              int* __restrict__ nidx) {
  int g = blockIdx.x, t = threadIdx.x;
  __shared__ float As1s[64*65];
  __shared__ float sp[64], s[64];
  __shared__ int perm[K1_];
  __shared__ float gate[K1_];
  for (int i = t; i < 4096; i += 256)
    As1s[(i >> 6)*65 + (i & 63)] = As1[i];
  if (t < 64) sp[t] = dots2[(g*64 + t)*2] + dots2[(g*64 + t)*2 + 1];
  __syncthreads();
  if (t < 64) {
    float acc = p1b[0];
    for (int j = 0; j < 64; ++j) acc = fmaf(As1s[t*65 + j], sp[j], acc);
    s[t] = acc;
  }
  __syncthreads();
  if (t < 64) {
    float si = s[t];
    int rank = 0;
    for (int j = 0; j < 64; ++j) {
      float sj = s[j];
      rank += (sj > si) || (sj == si && j < t);
    }
    nidx[g*64 + t] = (rank < K1_) ? rank : -1;
    if (rank < K1_) { perm[rank] = t; gate[rank] = tanhf(si); }
  }
  __syncthreads();
  if (t < K1_) {
    rowsrc[g*K1_ + t]  = g*64 + perm[t];
    rowgate[g*K1_ + t] = gate[t];
  }
}

// ---- gemm2g: xw2 = (gathered, gated y1) @ W2; 8x8 microtile, BM=128, BN=128 ---------
__global__ __launch_bounds__(256) void gemm2g(const float* __restrict__ y1,
                                              const int* __restrict__ rowsrc,
                                              const float* __restrict__ rowgate,
                                              const float* __restrict__ W2,
                                              float* __restrict__ xw2) {
  __shared__ __align__(16) float As[16][132];
  __shared__ __align__(16) float Bs[16][132];
  int t = threadIdx.x;
  int row0 = blockIdx.x * 128;
  int tx = t & 15, ty = t >> 4;
  float acc[8][8] = {};
  for (int k0 = 0; k0 < NHID; k0 += 16) {
#pragma unroll
    for (int p = 0; p < 2; ++p) {
      int rm = (t >> 2) + p*64, tq = t & 3;
      int sr = rowsrc[row0 + rm];
      float gt = rowgate[row0 + rm];
      float4 av = *(const float4*)(y1 + (size_t)sr * NHID + k0 + 4*tq);
      As[4*tq+0][rm] = av.x * gt; As[4*tq+1][rm] = av.y * gt;
      As[4*tq+2][rm] = av.z * gt; As[4*tq+3][rm] = av.w * gt;
    }
#pragma unroll
    for (int p = 0; p < 2; ++p) {
      int rk = (t >> 5) + p*8, cn = (t & 31)*4;
      *(float4*)&Bs[rk][cn] = *(const float4*)(W2 + (size_t)(k0 + rk)*NOUT + cn);
    }
    __syncthreads();
#pragma unroll
    for (int kk = 0; kk < 16; ++kk) {
      float a[8], b[8];
      *(float4*)&a[0] = *(const float4*)&As[kk][4*ty];
      *(float4*)&a[4] = *(const float4*)&As[kk][64 + 4*ty];
      *(float4*)&b[0] = *(const float4*)&Bs[kk][4*tx];
      *(float4*)&b[4] = *(const float4*)&Bs[kk][64 + 4*tx];
#pragma unroll
      for (int i = 0; i < 8; ++i)
#pragma unroll
        for (int j = 0; j < 8; ++j)
          acc[i][j] = fmaf(a[i], b[j], acc[i][j]);
    }
    __syncthreads();
  }
#pragma unroll
  for (int ih = 0; ih < 2; ++ih)
#pragma unroll
    for (int i = 0; i < 4; ++i) {
      int r = row0 + ih*64 + 4*ty + i;
#pragma unroll
      for (int jh = 0; jh < 2; ++jh) {
        float4 v = make_float4(acc[ih*4+i][jh*4+0], acc[ih*4+i][jh*4+1],
                               acc[ih*4+i][jh*4+2], acc[ih*4+i][jh*4+3]);
        *(float4*)(xw2 + (size_t)r * NOUT + jh*64 + 4*tx) = v;
      }
    }
}

// ---- mega2r: build A2/As2 + agg+BN+PReLU (y2 in regs) + dots + scores + rank-out ----
__global__ __launch_bounds__(256) void mega2r(const int* __restrict__ ei,
                                              const float* __restrict__ ew,
                                              const int* __restrict__ nidx,
                                              const float* __restrict__ xw2,
                                              const float* __restrict__ gc2b,
                                              const float* __restrict__ g2,
                                              const float* __restrict__ be2,
                                              const float* __restrict__ mu2,
                                              const float* __restrict__ v2,
                                              const float* __restrict__ pa2,
                                              const float* __restrict__ pw2,
                                              const float* __restrict__ p2b,
                                              float* __restrict__ out) {
  int g = blockIdx.x, t = threadIdx.x;
  __shared__ float A2t[64*68];                 // [j][c] zero-padded
  __shared__ float As2s[K1_*K1_];
  __shared__ __align__(16) float xs[K1_*132];
  __shared__ float dg[K1_], dgs[K1_], dis[K1_], diss[K1_], d[K1_], s[K1_], gA[K1_];
  __shared__ int nm[C_], rankA[K1_];
  __shared__ float4 zpart[8][32];

  for (int i = t; i < 64*68; i += 256) A2t[i] = 0.f;
  for (int i = t; i < K1_*K1_; i += 256) As2s[i] = 0.f;
  if (t < C_) nm[t] = nidx[g*C_ + t];
  if (t < K1_) { dg[t] = 1.f; dgs[t] = 1.f; }
  for (int p = 0; p < 7; ++p) {
    int idx = t + p*256;
    if (idx < K1_*32) {
      int r = idx >> 5, f4 = idx & 31;
      *(float4*)&xs[r*132 + f4*4] =
          *(const float4*)(xw2 + ((size_t)g*K1_ + r)*NOUT + f4*4);
    }
  }
  int eR[2], eC[2]; float eW[2];
#pragma unroll
  for (int p = 0; p < 2; ++p) {
    int e = t + p*256;
    eR[p] = ei[e]; eC[p] = ei[E_ + e]; eW[p] = ew[e];
  }
  __syncthreads();
  int nr[2], nc[2]; bool val[2];
#pragma unroll
  for (int p = 0; p < 2; ++p) {
    nr[p] = nm[eR[p]]; nc[p] = nm[eC[p]];
    val[p] = (nr[p] >= 0) && (nc[p] >= 0);
    if (val[p]) { atomicAdd(&dg[nc[p]], eW[p]); atomicAdd(&dgs[nc[p]], 1.f); }
  }
  __syncthreads();
  if (t < K1_) { dis[t] = rsqrtf(dg[t]); diss[t] = rsqrtf(dgs[t]); }
  __syncthreads();
#pragma unroll
  for (int p = 0; p < 2; ++p) {
    if (val[p]) {
      atomicAdd(&A2t[nr[p]*68 + nc[p]],  dis[nr[p]] * eW[p] * dis[nc[p]]);
      atomicAdd(&As2s[nc[p]*K1_ + nr[p]], diss[nr[p]] * diss[nc[p]]);
    }
  }
  if (t < K1_) {
    atomicAdd(&A2t[t*68 + t],   dis[t]*dis[t]);
    atomicAdd(&As2s[t*K1_ + t], diss[t]*diss[t]);
  }
  __syncthreads();
  // agg: rows c = ty*8+i, cols 4*tx
  int tx = t & 31, ty = t >> 5;
  float4 scv, shv, pwv;
  {
    int col = 4*tx;
    float4 gv = *(const float4*)(g2 + col);
    float4 vv = *(const float4*)(v2 + col);
    float4 bv = *(const float4*)(be2 + col);
    float4 mv = *(const float4*)(mu2 + col);
    float4 b0 = *(const float4*)(gc2b + col);
    scv.x = gv.x * rsqrtf(vv.x + 1e-5f); scv.y = gv.y * rsqrtf(vv.y + 1e-5f);
    scv.z = gv.z * rsqrtf(vv.z + 1e-5f); scv.w = gv.w * rsqrtf(vv.w + 1e-5f);
    shv = make_float4((b0.x - mv.x)*scv.x + bv.x, (b0.y - mv.y)*scv.y + bv.y,
                      (b0.z - mv.z)*scv.z + bv.z, (b0.w - mv.w)*scv.w + bv.w);
    pwv = *(const float4*)(pw2 + col);
  }
  float a2v = pa2[0];
  float acc[8][4] = {};
  for (int j = 0; j < K1_; ++j) {
    float a[8];
    *(float4*)&a[0] = *(const float4*)&A2t[j*68 + ty*8];
    *(float4*)&a[4] = *(const float4*)&A2t[j*68 + ty*8 + 4];
    float4 xv = *(const float4*)&xs[j*132 + tx*4];
#pragma unroll
    for (int i = 0; i < 8; ++i) {
      acc[i][0] = fmaf(a[i], xv.x, acc[i][0]);
      acc[i][1] = fmaf(a[i], xv.y, acc[i][1]);
      acc[i][2] = fmaf(a[i], xv.z, acc[i][2]);
      acc[i][3] = fmaf(a[i], xv.w, acc[i][3]);
    }
  }
  // BN + PReLU in registers (y2 never leaves the block); node dots
#pragma unroll
  for (int i = 0; i < 8; ++i) {
    int c = ty*8 + i;
    if (c < K1_) {
      float4 o;
      o.x = acc[i][0]*scv.x + shv.x; o.y = acc[i][1]*scv.y + shv.y;
      o.z = acc[i][2]*scv.z + shv.z; o.w = acc[i][3]*scv.w + shv.w;
      o.x = o.x >= 0.f ? o.x : a2v*o.x; o.y = o.y >= 0.f ? o.y : a2v*o.y;
      o.z = o.z >= 0.f ? o.z : a2v*o.z; o.w = o.w >= 0.f ? o.w : a2v*o.w;
      acc[i][0] = o.x; acc[i][1] = o.y; acc[i][2] = o.z; acc[i][3] = o.w;
      float dp = o.x*pwv.x + o.y*pwv.y + o.z*pwv.z + o.w*pwv.w;
      dp += __shfl_xor(dp, 1);
      dp += __shfl_xor(dp, 2);
      dp += __shfl_xor(dp, 4);
      dp += __shfl_xor(dp, 8);
      dp += __shfl_xor(dp, 16);
      if (tx == 0) d[c] = dp;
    }
  }
  __syncthreads();
  if (t < K1_) {
    float sv = p2b[0];
    for (int j = 0; j < K1_; ++j) sv = fmaf(As2s[t*K1_ + j], d[j], sv);
    s[t] = sv;
  }
  __syncthreads();
  if (t < K1_) {
    float si = s[t];
    int rank = 0;
    for (int j = 0; j < K1_; ++j) {
      float sj = s[j];
      rank += (sj > si) || (sj == si && j < t);
    }
    rankA[t] = rank;
    gA[t] = tanhf(si);
  }
  __syncthreads();
  // rank-directed output: row c -> slot rankA[c] if selected
  float4 zp = make_float4(0.f, 0.f, 0.f, 0.f);
#pragma unroll
  for (int i = 0; i < 8; ++i) {
    int c = ty*8 + i;
    if (c < K1_) {
      int r = rankA[c];
      if (r < K2_) {
        float gt = gA[c];
        float4 v = make_float4(acc[i][0]*gt, acc[i][1]*gt, acc[i][2]*gt, acc[i][3]*gt);
        *(float4*)(out + ((size_t)g*K2_ + r)*NOUT + 4*tx) = v;
        zp.x += v.x; zp.y += v.y; zp.z += v.z; zp.w += v.w;
      }
    }
  }
  zpart[ty][tx] = zp;
  __syncthreads();
  if (t < 32) {
    float4 z = make_float4(0.f, 0.f, 0.f, 0.f);
#pragma unroll
    for (int k = 0; k < 8; ++k) {
      float4 v = zpart[k][t];
      z.x += v.x; z.y += v.y; z.z += v.z; z.w += v.w;
    }
    const float inv = 1.0f / (float)K2_;
    z.x *= inv; z.y *= inv; z.z *= inv; z.w *= inv;
    *(float4*)(out + (size_t)G_*K2_*NOUT + (size_t)g*NOUT + 4*t) = z;
  }
}

extern "C" void kernel_launch(void* const* d_in, const int* in_sizes, int n_in,
                              void* d_out, int out_size, void* d_ws, size_t ws_size,
                              hipStream_t stream) {
  const float* h    = (const float*)d_in[0];
  const int*   ei   = (const int*)  d_in[1];
  const float* ew   = (const float*)d_in[2];
  const float* gc1w = (const float*)d_in[3];
  const float* gc1b = (const float*)d_in[4];
  const float* bn1g = (const float*)d_in[5];
  const float* bn1b = (const float*)d_in[6];
  const float* bn1m = (const float*)d_in[7];
  const float* bn1v = (const float*)d_in[8];
  const float* pr1a = (const float*)d_in[9];
  const float* p1w  = (const float*)d_in[10];
  const float* p1b  = (const float*)d_in[11];
  const float* gc2w = (const float*)d_in[12];
  const float* gc2b = (const float*)d_in[13];
  const float* bn2g = (const float*)d_in[14];
  const float* bn2b = (const float*)d_in[15];
  const float* bn2m = (const float*)d_in[16];
  const float* bn2v = (const float*)d_in[17];
  const float* pr2a = (const float*)d_in[18];
  const float* p2w  = (const float*)d_in[19];
  const float* p2b  = (const float*)d_in[20];

  float* w = (float*)d_ws;
  // float offsets
  float* A1      = w;                       // 4096
  float* As1     = w + 4096;                // 4096
  float* dots2   = w + 8192;                // 131072 (65536 x 2)
  int*   nidx    = (int*)(w + 139264);      // 65536
  int*   rowsrc  = (int*)(w + 204800);      // 53248
  float* rowgate = w + 258048;              // 53248
  float* xa2     = w + 327680;              // 8388608  (32*64*128*32)
  float* y1      = w + 8716288;             // 16777216 (65536*256)  end 25493504 fl
  float* xw2     = xa2;                     // 6815744 <= 8388608 (xa2 dead after gemm1e)

  build_A1<<<1, 256, 0, stream>>>(ei, ew, A1, As1);
  preagg_b<<<1024, 256, 0, stream>>>(h, A1, xa2);
  gemm1e<<<dim3(256, 2), 256, 0, stream>>>(xa2, gc1w, gc1b, bn1g, bn1b, bn1m, bn1v,
                                           pr1a, p1w, y1, dots2);
  pool1s<<<G_, 256, 0, stream>>>(dots2, As1, p1b, rowsrc, rowgate, nidx);
  gemm2g<<<416, 256, 0, stream>>>(y1, rowsrc, rowgate, gc2w, xw2);
  mega2r<<<G_, 256, 0, stream>>>(ei, ew, nidx, xw2, gc2b, bn2g, bn2b, bn2m, bn2v,
                                 pr2a, p2w, p2b, (float*)d_out);
}